// Round 13
// baseline (825.920 us; speedup 1.0000x reference)
//
#include <hip/hip_runtime.h>

typedef __bf16 bf16x8 __attribute__((ext_vector_type(8)));
typedef float f32x4 __attribute__((ext_vector_type(4)));
typedef unsigned int uint32x4 __attribute__((ext_vector_type(4)));

#define DD 256
#define VV 1024
#define BN 16
#define KC1 36    // extended-K chunks of 8 (288/8): 32 data + c2 + zeros
#define WVA 8     // waves in kernel A
#define VCH 128   // V-chunk per wave in kernel A
#define TILES 8   // tiles per persistent block (4096 tiles / 512 blocks)

__device__ __forceinline__ unsigned short f2bf(float f) {
    unsigned int b = __float_as_uint(f);
    b += 0x7FFFu + ((b >> 16) & 1u);
    return (unsigned short)(b >> 16);
}

// async global->LDS, 16B per lane. LDS dst must be WAVE-UNIFORM base
// (HW adds lane*16); global src is per-lane.
typedef __attribute__((address_space(3))) unsigned int lds_uint;
typedef __attribute__((address_space(1))) const unsigned int glb_uint;
__device__ __forceinline__ void dma16(const float* g, float* l) {
    __builtin_amdgcn_global_load_lds((glb_uint*)g, (lds_uint*)l, 16, 0, 0);
}

// Prep: fragment-major, sigma-permuted codebook layouts.
// sigma: element d -> kc = (d>>5)*4 + ((d>>2)&3), j = (d&3) + ((d>>4)&1)*4.
__global__ __launch_bounds__(256) void vq_prep_kernel(
    const float* __restrict__ cb,
    unsigned short* __restrict__ cbA,   // [V/16][KC1][16][8]
    unsigned short* __restrict__ cbB)   // [D/16][128][16][8]
{
    int v = blockIdx.x;
    int t = threadIdx.x;
    float val = cb[(size_t)v * DD + t];
    unsigned short h = f2bf(val);
    const int vtile = v >> 4, vi = v & 15;
    const int kc_t = (t >> 5) * 4 + ((t >> 2) & 3);
    const int j_t  = (t & 3) + ((t >> 4) & 1) * 4;
    cbA[(((size_t)vtile * KC1 + kc_t) * 16 + vi) * 8 + j_t] = h;
    const int kcv = (v >> 5) * 4 + ((v >> 2) & 3);
    const int jv  = (v & 3) + ((v >> 4) & 1) * 4;
    cbB[(((size_t)(t >> 4) * 128 + kcv) * 16 + (t & 15)) * 8 + jv] = h;

    float p = val * val;
#pragma unroll
    for (int d = 1; d < 64; d <<= 1) p += __shfl_xor(p, d);
    __shared__ float ps[4];
    if ((t & 63) == 0) ps[t >> 6] = p;
    __syncthreads();
    if (t < 32) {
        float c2 = ps[0] + ps[1] + ps[2] + ps[3];
        float m = -0.5f * c2;
        unsigned short hi = f2bf(m);
        float hif = __uint_as_float((unsigned int)hi << 16);
        unsigned short lo = f2bf(m - hif);
        unsigned short o = (t == 0) ? hi : ((t == 1) ? lo : (unsigned short)0);
        cbA[(((size_t)vtile * KC1 + 32 + (t >> 3)) * 16 + vi) * 8 + (t & 7)] = o;
    }
}

// Kernel A (persistent): GEMM1 + fused no-max gumbel-softmax -> out_p.
// 512 blocks x 8 tiles; gumbel DMA for tile i+1 issued right after tile i's
// softmax-read barrier -> DMA flies under Z/out_p stores + x/afr + GEMM1 of
// the next tile. __syncthreads() barriers (full fence semantics).
__global__ __launch_bounds__(512, 4) void vq_softmax_kernel(
    const float* __restrict__ x,          // [N][D]
    const float* __restrict__ gum,        // [N][V]
    const unsigned short* __restrict__ cbA,
    float* __restrict__ out_p)            // [N][V]
{
    __shared__ __align__(16) float gbuf[BN * VV];   // 64 KB gumbel u (f32)
    __shared__ float sred[WVA * BN];                // 512 B Z partials

    const int tid  = threadIdx.x;
    const int wave = tid >> 6;    // 0..7
    const int lane = tid & 63;
    const int lrow = (lane >> 4) & 3;
    const int lcol = lane & 15;
    const int vb   = wave * VCH;
    const int laneoff = lrow * 128 + lcol * 8;
    const int tile0 = blockIdx.x * TILES;

    // ---- prologue: DMA gumbel for tile 0 ----
    {
        const int row0 = tile0 * BN;
#pragma unroll
        for (int h = 0; h < 2; ++h) {
            const int r = wave * 2 + h;
            const float* gsrc = gum + (size_t)(row0 + r) * VV;
#pragma unroll
            for (int i = 0; i < 4; ++i) {
                const int g = i * 64 + lane;
                dma16(gsrc + ((g ^ (r & 7)) << 2), &gbuf[r * VV + i * 256]);
            }
        }
    }

#pragma unroll 1
    for (int it = 0; it < TILES; ++it) {
        const int row0 = (tile0 + it) * BN;

        // ---- x: direct per-lane loads (transient), afr + x2 ----
        // FR ORDER: fr[0..3] = xa.xyzw (sigma slots 0..3), fr[4..7] = xb.xyzw
        // (sigma slots 4..7). R11/R12 used v8[2j]/v8[2j+1] here — a fragment
        // permutation NOT applied to cbA -> garbage GEMM1 (absmax 0.98).
        bf16x8 afr[9];
        float x2 = 0.f;
        {
            const float* xrow = x + (size_t)(row0 + lcol) * DD + lrow * 4;
            float4 xa[8], xb[8];
#pragma unroll
            for (int kt = 0; kt < 8; ++kt) {
                xa[kt] = *reinterpret_cast<const float4*>(xrow + kt * 32);
                xb[kt] = *reinterpret_cast<const float4*>(xrow + kt * 32 + 16);
            }
#pragma unroll
            for (int kt = 0; kt < 8; ++kt) {
                float va[4] = {xa[kt].x, xa[kt].y, xa[kt].z, xa[kt].w};
                float vb4[4] = {xb[kt].x, xb[kt].y, xb[kt].z, xb[kt].w};
                bf16x8 fr;
#pragma unroll
                for (int j = 0; j < 4; ++j) {
                    x2 += va[j] * va[j] + vb4[j] * vb4[j];
                    fr[j]     = (__bf16)va[j];
                    fr[j + 4] = (__bf16)vb4[j];
                }
                afr[kt] = fr;
            }
            x2 += __shfl_xor(x2, 16);
            x2 += __shfl_xor(x2, 32);   // full-row x2 of row lcol
            uint32x4 w = {0u, 0u, 0u, 0u};
            if (lrow == 0) w[0] = 0x3F803F80u;  // bf16 1.0 pair at c2 slots
            afr[8] = __builtin_bit_cast(bf16x8, w);
        }

        // ---- GEMM1 (swapped): acc[nt]: v = vb+16nt+4lrow+r, x-row = lcol ----
        f32x4 acc[8];
#pragma unroll
        for (int nt = 0; nt < 8; ++nt) acc[nt] = (f32x4){0.f, 0.f, 0.f, 0.f};
#pragma unroll
        for (int nt = 0; nt < 8; ++nt) {
            const unsigned short* ap =
                cbA + ((size_t)(vb >> 4) + nt) * (KC1 * 128) + laneoff;
#pragma unroll
            for (int kt = 0; kt < 9; ++kt) {
                bf16x8 cfr = __builtin_bit_cast(bf16x8,
                    *reinterpret_cast<const uint32x4*>(ap + kt * 512));
                acc[nt] = __builtin_amdgcn_mfma_f32_16x16x32_bf16(cfr, afr[kt], acc[nt], 0, 0, 0);
            }
        }

        // BARRIER1: full fence + vmcnt drain -> gbuf(it) DMA landed for ALL waves.
        __syncthreads();

        // ---- gumbel from LDS + single-pass no-max softmax ----
        f32x4 u4[8];
#pragma unroll
        for (int nt = 0; nt < 8; ++nt) {
            const int gg = ((vb >> 2) + nt * 4 + lrow) ^ (lcol & 7);
            u4[nt] = *reinterpret_cast<const f32x4*>(&gbuf[lcol * VV + gg * 4]);
        }

        float ss = 0.f;
        f32x4 pe[8];
#pragma unroll
        for (int nt = 0; nt < 8; ++nt) {
#pragma unroll
            for (int r = 0; r < 4; ++r) {
                float u = fminf(fmaxf(u4[nt][r], 1e-10f), 1.0f - 1e-10f);
                float l2u = __builtin_amdgcn_logf(u);           // log2(u)
                float t = u - 1.0f;
                float pp = t * (1.0f + t * (-0.5f + t * (0.33333333f + t * (-0.25f + t * 0.2f))));
                float w = (u >= 0.984375f) ? -pp : (l2u * -0.69314718f);
                float l2w = __builtin_amdgcn_logf(w);           // log2(w)
                float d2 = fmaxf(__builtin_fmaf(-2.0f, acc[nt][r], x2), 1e-12f);
                float dist = __builtin_amdgcn_sqrtf(d2);
                float lg2 = __builtin_fmaf(-0.72134752f, dist, -0.5f * l2w);
                float e = __builtin_amdgcn_exp2f(lg2);
                pe[nt][r] = e;
                ss += e;
            }
        }
        ss += __shfl_xor(ss, 16);
        ss += __shfl_xor(ss, 32);   // row sum for row lcol (this V-chunk)

        if (lane < 16) sred[wave * 16 + lane] = ss;
        // BARRIER2: sred visible; all waves done reading gbuf(it).
        __syncthreads();

        // ---- issue DMA for tile it+1 (flies until BARRIER1 of next tile) ----
        if (it + 1 < TILES) {
            const int nrow0 = (tile0 + it + 1) * BN;
#pragma unroll
            for (int h = 0; h < 2; ++h) {
                const int r = wave * 2 + h;
                const float* gsrc = gum + (size_t)(nrow0 + r) * VV;
#pragma unroll
                for (int i = 0; i < 4; ++i) {
                    const int g = i * 64 + lane;
                    dma16(gsrc + ((g ^ (r & 7)) << 2), &gbuf[r * VV + i * 256]);
                }
            }
        }

        // ---- Z, rinv, out_p stores ----
        float Z = 0.f;
#pragma unroll
        for (int w = 0; w < WVA; ++w) Z += sred[w * 16 + lcol];
        const float rinv = 1.0f / Z;

        float* oprow = out_p + (size_t)(row0 + lcol) * VV + vb + lrow * 4;
#pragma unroll
        for (int nt = 0; nt < 8; ++nt)
            *reinterpret_cast<float4*>(oprow + nt * 16) =
                (float4){pe[nt][0] * rinv, pe[nt][1] * rinv,
                         pe[nt][2] * rinv, pe[nt][3] * rinv};
    }
}

// Kernel B: out_q = prob @ cb. 64 rows/block (4 row-groups of 16), 4 waves
// owning D-chunks of 64; cbB fragments reused across the 4 row-groups.
__global__ __launch_bounds__(256, 4) void vq_gemm2_kernel(
    const float* __restrict__ out_p,      // [N][V]
    const unsigned short* __restrict__ cbB,
    float* __restrict__ out_q)            // [N][D]
{
    const int tid  = threadIdx.x;
    const int wave = tid >> 6;
    const int lane = tid & 63;
    const int lrow = (lane >> 4) & 3;
    const int lcol = lane & 15;
    const int row0 = blockIdx.x * 64;
    const int dbw  = wave * 64;
    const int laneoff = lrow * 128 + lcol * 8;

    const unsigned short* bb =
        cbB + (size_t)(dbw >> 4) * (128 * 128) + laneoff;

    f32x4 q[4][4];
#pragma unroll
    for (int g = 0; g < 4; ++g)
#pragma unroll
        for (int nt = 0; nt < 4; ++nt) q[g][nt] = (f32x4){0.f, 0.f, 0.f, 0.f};

#pragma unroll 2
    for (int kt = 0; kt < 32; ++kt) {
        bf16x8 bfr[4];
#pragma unroll
        for (int nt = 0; nt < 4; ++nt)
            bfr[nt] = __builtin_bit_cast(bf16x8,
                *reinterpret_cast<const uint32x4*>(bb + nt * 16384 + kt * 512));
#pragma unroll
        for (int g = 0; g < 4; ++g) {
            const float* pr =
                out_p + (size_t)(row0 + g * 16 + lcol) * VV + kt * 32 + lrow * 4;
            f32x4 a = *reinterpret_cast<const f32x4*>(pr);
            f32x4 b = *reinterpret_cast<const f32x4*>(pr + 16);
            bf16x8 pfr;
#pragma unroll
            for (int j = 0; j < 4; ++j) {
                pfr[j]     = (__bf16)a[j];
                pfr[j + 4] = (__bf16)b[j];
            }
#pragma unroll
            for (int nt = 0; nt < 4; ++nt)
                q[g][nt] = __builtin_amdgcn_mfma_f32_16x16x32_bf16(pfr, bfr[nt], q[g][nt], 0, 0, 0);
        }
    }

#pragma unroll
    for (int g = 0; g < 4; ++g) {
        float* qrow0 = out_q + (size_t)(row0 + g * 16 + lrow * 4) * DD + dbw + lcol;
#pragma unroll
        for (int r = 0; r < 4; ++r) {
            float* qr = qrow0 + r * DD;
#pragma unroll
            for (int nt = 0; nt < 4; ++nt) qr[nt * 16] = q[g][nt][r];
        }
    }
}

extern "C" void kernel_launch(void* const* d_in, const int* in_sizes, int n_in,
                              void* d_out, int out_size, void* d_ws, size_t ws_size,
                              hipStream_t stream) {
    (void)in_sizes; (void)n_in; (void)out_size; (void)ws_size;
    const float* x   = (const float*)d_in[0];   // [16,4096,256]
    const float* cb  = (const float*)d_in[1];   // [1024,256]
    const float* gum = (const float*)d_in[2];   // [65536,1024]

    const int N = 16 * 4096;
    float* out_q = (float*)d_out;                       // [N][256]
    float* out_p = out_q + (size_t)N * DD;              // [N][1024]

    unsigned short* cbA = (unsigned short*)d_ws;        // 576 KB fragment-major
    unsigned short* cbB = cbA + (size_t)64 * KC1 * 128; // 512 KB fragment-major
    vq_prep_kernel<<<VV, 256, 0, stream>>>(cb, cbA, cbB);
    vq_softmax_kernel<<<(N / BN) / TILES, 512, 0, stream>>>(x, gum, cbA, out_p);
    vq_gemm2_kernel<<<N / 64, 256, 0, stream>>>(out_p, cbB, out_q);
}

// Round 14
// 659.059 us; speedup vs baseline: 1.2532x; 1.2532x over previous
//
#include <hip/hip_runtime.h>

typedef __bf16 bf16x8 __attribute__((ext_vector_type(8)));
typedef float f32x4 __attribute__((ext_vector_type(4)));
typedef unsigned int uint32x4 __attribute__((ext_vector_type(4)));

#define DD 256
#define VV 1024
#define BN 16
#define KC1 36    // extended-K chunks of 8 (288/8): 32 data + c2 + zeros
#define WVA 8     // waves in kernel A
#define VCH 128   // V-chunk per wave in kernel A
#define TILES 8   // tiles per persistent block (4096 tiles / 512 blocks)

__device__ __forceinline__ unsigned short f2bf(float f) {
    unsigned int b = __float_as_uint(f);
    b += 0x7FFFu + ((b >> 16) & 1u);
    return (unsigned short)(b >> 16);
}

// async global->LDS, 16B per lane. LDS dst must be WAVE-UNIFORM base
// (HW adds lane*16); global src is per-lane.
typedef __attribute__((address_space(3))) unsigned int lds_uint;
typedef __attribute__((address_space(1))) const unsigned int glb_uint;
__device__ __forceinline__ void dma16(const float* g, float* l) {
    __builtin_amdgcn_global_load_lds((glb_uint*)g, (lds_uint*)l, 16, 0, 0);
}

// Prep: fragment-major, sigma-permuted codebook layouts.
// sigma: element d -> kc = (d>>5)*4 + ((d>>2)&3), j = (d&3) + ((d>>4)&1)*4.
__global__ __launch_bounds__(256) void vq_prep_kernel(
    const float* __restrict__ cb,
    unsigned short* __restrict__ cbA,   // [V/16][KC1][16][8]
    unsigned short* __restrict__ cbB)   // [D/16][128][16][8]
{
    int v = blockIdx.x;
    int t = threadIdx.x;
    float val = cb[(size_t)v * DD + t];
    unsigned short h = f2bf(val);
    const int vtile = v >> 4, vi = v & 15;
    const int kc_t = (t >> 5) * 4 + ((t >> 2) & 3);
    const int j_t  = (t & 3) + ((t >> 4) & 1) * 4;
    cbA[(((size_t)vtile * KC1 + kc_t) * 16 + vi) * 8 + j_t] = h;
    const int kcv = (v >> 5) * 4 + ((v >> 2) & 3);
    const int jv  = (v & 3) + ((v >> 4) & 1) * 4;
    cbB[(((size_t)(t >> 4) * 128 + kcv) * 16 + (t & 15)) * 8 + jv] = h;

    float p = val * val;
#pragma unroll
    for (int d = 1; d < 64; d <<= 1) p += __shfl_xor(p, d);
    __shared__ float ps[4];
    if ((t & 63) == 0) ps[t >> 6] = p;
    __syncthreads();
    if (t < 32) {
        float c2 = ps[0] + ps[1] + ps[2] + ps[3];
        float m = -0.5f * c2;
        unsigned short hi = f2bf(m);
        float hif = __uint_as_float((unsigned int)hi << 16);
        unsigned short lo = f2bf(m - hif);
        unsigned short o = (t == 0) ? hi : ((t == 1) ? lo : (unsigned short)0);
        cbA[(((size_t)vtile * KC1 + 32 + (t >> 3)) * 16 + vi) * 8 + (t & 7)] = o;
    }
}

// Kernel A (persistent): GEMM1 + fused no-max gumbel-softmax -> out_p.
// 512 blocks x 8 tiles. Both x and gumbel staged to LDS by global_load_lds;
// DMA(it+1) issued after B1 -> overlaps GEMM1+softmax of tile it (drained at
// B2, a __syncthreads). No register staging of x/gum -> no spills (R13's
// regression: xa/xb+pe+u4+acc > 128 regs -> 540 MB scratch traffic).
__global__ __launch_bounds__(512, 4) void vq_softmax_kernel(
    const float* __restrict__ x,          // [N][D]
    const float* __restrict__ gum,        // [N][V]
    const unsigned short* __restrict__ cbA,
    float* __restrict__ out_p)            // [N][V]
{
    __shared__ __align__(16) float xbuf[BN * DD];   // 16 KB
    __shared__ __align__(16) float gbuf[BN * VV];   // 64 KB
    __shared__ float sred[WVA * BN];                // 512 B

    const int tid  = threadIdx.x;
    const int wave = tid >> 6;    // 0..7
    const int lane = tid & 63;
    const int lrow = (lane >> 4) & 3;
    const int lcol = lane & 15;
    const int vb   = wave * VCH;
    const int laneoff = lrow * 128 + lcol * 8;
    const int tile0 = blockIdx.x * TILES;

    // ---- prologue: DMA x + gumbel for tile 0 ----
    {
        const int row0 = tile0 * BN;
#pragma unroll
        for (int h = 0; h < 2; ++h) {
            const int r = wave * 2 + h;
            dma16(x + (size_t)(row0 + r) * DD + (((lane ^ (r & 7)) & 63) << 2),
                  &xbuf[r * DD]);
        }
#pragma unroll
        for (int h = 0; h < 2; ++h) {
            const int r = wave * 2 + h;
            const float* gsrc = gum + (size_t)(row0 + r) * VV;
#pragma unroll
            for (int i = 0; i < 4; ++i) {
                const int g = i * 64 + lane;
                dma16(gsrc + ((g ^ (r & 7)) << 2), &gbuf[r * VV + i * 256]);
            }
        }
    }

#pragma unroll 1
    for (int it = 0; it < TILES; ++it) {
        const int row0 = (tile0 + it) * BN;

        // B0: DMA(it) landed for all waves (full fence + vmcnt drain).
        __syncthreads();

        // ---- gumbel tile -> u4 regs (consume gbuf early) ----
        f32x4 u4[8];
#pragma unroll
        for (int nt = 0; nt < 8; ++nt) {
            const int gg = ((vb >> 2) + nt * 4 + lrow) ^ (lcol & 7);
            u4[nt] = *reinterpret_cast<const f32x4*>(&gbuf[lcol * VV + gg * 4]);
        }

        // ---- afr from xbuf (sigma slots) + x2 (R10-verified layout) ----
        bf16x8 afr[9];
        float x2 = 0.f;
#pragma unroll
        for (int kt = 0; kt < 8; ++kt) {
            const int g1 = (kt * 8 + lrow) ^ (lcol & 7);
            const int g2 = (kt * 8 + lrow + 4) ^ (lcol & 7);
            f32x4 a = *reinterpret_cast<const f32x4*>(&xbuf[lcol * DD + g1 * 4]);
            f32x4 b = *reinterpret_cast<const f32x4*>(&xbuf[lcol * DD + g2 * 4]);
            bf16x8 fr;
#pragma unroll
            for (int j = 0; j < 4; ++j) {
                x2 += a[j] * a[j] + b[j] * b[j];
                fr[j]     = (__bf16)a[j];
                fr[j + 4] = (__bf16)b[j];
            }
            afr[kt] = fr;
        }
        x2 += __shfl_xor(x2, 16);
        x2 += __shfl_xor(x2, 32);   // full-row x2 of row lcol
        {
            uint32x4 w = {0u, 0u, 0u, 0u};
            if (lrow == 0) w[0] = 0x3F803F80u;  // bf16 1.0 pair at c2 slots
            afr[8] = __builtin_bit_cast(bf16x8, w);
        }

        // B1: xbuf + gbuf fully consumed into registers by all waves.
        __syncthreads();

        // ---- issue DMA for tile it+1 (overlaps GEMM1 + softmax below) ----
        if (it + 1 < TILES) {
            const int nrow0 = (tile0 + it + 1) * BN;
#pragma unroll
            for (int h = 0; h < 2; ++h) {
                const int r = wave * 2 + h;
                dma16(x + (size_t)(nrow0 + r) * DD + (((lane ^ (r & 7)) & 63) << 2),
                      &xbuf[r * DD]);
            }
#pragma unroll
            for (int h = 0; h < 2; ++h) {
                const int r = wave * 2 + h;
                const float* gsrc = gum + (size_t)(nrow0 + r) * VV;
#pragma unroll
                for (int i = 0; i < 4; ++i) {
                    const int g = i * 64 + lane;
                    dma16(gsrc + ((g ^ (r & 7)) << 2), &gbuf[r * VV + i * 256]);
                }
            }
        }

        // ---- GEMM1 (swapped): acc[nt]: v = vb+16nt+4lrow+r, x-row = lcol ----
        f32x4 acc[8];
#pragma unroll
        for (int nt = 0; nt < 8; ++nt) acc[nt] = (f32x4){0.f, 0.f, 0.f, 0.f};
#pragma unroll
        for (int nt = 0; nt < 8; ++nt) {
            const unsigned short* ap =
                cbA + ((size_t)(vb >> 4) + nt) * (KC1 * 128) + laneoff;
#pragma unroll
            for (int kt = 0; kt < 9; ++kt) {
                bf16x8 cfr = __builtin_bit_cast(bf16x8,
                    *reinterpret_cast<const uint32x4*>(ap + kt * 512));
                acc[nt] = __builtin_amdgcn_mfma_f32_16x16x32_bf16(cfr, afr[kt], acc[nt], 0, 0, 0);
            }
        }

        // ---- single-pass no-max softmax (u4, acc -> pe, ss) ----
        float ss = 0.f;
        f32x4 pe[8];
#pragma unroll
        for (int nt = 0; nt < 8; ++nt) {
#pragma unroll
            for (int r = 0; r < 4; ++r) {
                float u = fminf(fmaxf(u4[nt][r], 1e-10f), 1.0f - 1e-10f);
                float l2u = __builtin_amdgcn_logf(u);           // log2(u)
                float t = u - 1.0f;
                float pp = t * (1.0f + t * (-0.5f + t * (0.33333333f + t * (-0.25f + t * 0.2f))));
                float w = (u >= 0.984375f) ? -pp : (l2u * -0.69314718f);
                float l2w = __builtin_amdgcn_logf(w);           // log2(w)
                float d2 = fmaxf(__builtin_fmaf(-2.0f, acc[nt][r], x2), 1e-12f);
                float dist = __builtin_amdgcn_sqrtf(d2);
                float lg2 = __builtin_fmaf(-0.72134752f, dist, -0.5f * l2w);
                float e = __builtin_amdgcn_exp2f(lg2);
                pe[nt][r] = e;
                ss += e;
            }
        }
        ss += __shfl_xor(ss, 16);
        ss += __shfl_xor(ss, 32);   // row sum for row lcol (this V-chunk)

        if (lane < 16) sred[wave * 16 + lane] = ss;
        // B2: sred visible; DMA(it+1) drained (its window was GEMM1+softmax).
        __syncthreads();

        // ---- Z, rinv, out_p stores ----
        float Z = 0.f;
#pragma unroll
        for (int w = 0; w < WVA; ++w) Z += sred[w * 16 + lcol];
        const float rinv = 1.0f / Z;

        float* oprow = out_p + (size_t)(row0 + lcol) * VV + vb + lrow * 4;
#pragma unroll
        for (int nt = 0; nt < 8; ++nt)
            *reinterpret_cast<float4*>(oprow + nt * 16) =
                (float4){pe[nt][0] * rinv, pe[nt][1] * rinv,
                         pe[nt][2] * rinv, pe[nt][3] * rinv};
    }
}

// Kernel B: out_q = prob @ cb. 64 rows/block (4 row-groups of 16), 4 waves
// owning D-chunks of 64; cbB fragments reused across the 4 row-groups.
__global__ __launch_bounds__(256, 4) void vq_gemm2_kernel(
    const float* __restrict__ out_p,      // [N][V]
    const unsigned short* __restrict__ cbB,
    float* __restrict__ out_q)            // [N][D]
{
    const int tid  = threadIdx.x;
    const int wave = tid >> 6;
    const int lane = tid & 63;
    const int lrow = (lane >> 4) & 3;
    const int lcol = lane & 15;
    const int row0 = blockIdx.x * 64;
    const int dbw  = wave * 64;
    const int laneoff = lrow * 128 + lcol * 8;

    const unsigned short* bb =
        cbB + (size_t)(dbw >> 4) * (128 * 128) + laneoff;

    f32x4 q[4][4];
#pragma unroll
    for (int g = 0; g < 4; ++g)
#pragma unroll
        for (int nt = 0; nt < 4; ++nt) q[g][nt] = (f32x4){0.f, 0.f, 0.f, 0.f};

#pragma unroll 2
    for (int kt = 0; kt < 32; ++kt) {
        bf16x8 bfr[4];
#pragma unroll
        for (int nt = 0; nt < 4; ++nt)
            bfr[nt] = __builtin_bit_cast(bf16x8,
                *reinterpret_cast<const uint32x4*>(bb + nt * 16384 + kt * 512));
#pragma unroll
        for (int g = 0; g < 4; ++g) {
            const float* pr =
                out_p + (size_t)(row0 + g * 16 + lcol) * VV + kt * 32 + lrow * 4;
            f32x4 a = *reinterpret_cast<const f32x4*>(pr);
            f32x4 b = *reinterpret_cast<const f32x4*>(pr + 16);
            bf16x8 pfr;
#pragma unroll
            for (int j = 0; j < 4; ++j) {
                pfr[j]     = (__bf16)a[j];
                pfr[j + 4] = (__bf16)b[j];
            }
#pragma unroll
            for (int nt = 0; nt < 4; ++nt)
                q[g][nt] = __builtin_amdgcn_mfma_f32_16x16x32_bf16(pfr, bfr[nt], q[g][nt], 0, 0, 0);
        }
    }

#pragma unroll
    for (int g = 0; g < 4; ++g) {
        float* qrow0 = out_q + (size_t)(row0 + g * 16 + lrow * 4) * DD + dbw + lcol;
#pragma unroll
        for (int r = 0; r < 4; ++r) {
            float* qr = qrow0 + r * DD;
#pragma unroll
            for (int nt = 0; nt < 4; ++nt) qr[nt * 16] = q[g][nt][r];
        }
    }
}

extern "C" void kernel_launch(void* const* d_in, const int* in_sizes, int n_in,
                              void* d_out, int out_size, void* d_ws, size_t ws_size,
                              hipStream_t stream) {
    (void)in_sizes; (void)n_in; (void)out_size; (void)ws_size;
    const float* x   = (const float*)d_in[0];   // [16,4096,256]
    const float* cb  = (const float*)d_in[1];   // [1024,256]
    const float* gum = (const float*)d_in[2];   // [65536,1024]

    const int N = 16 * 4096;
    float* out_q = (float*)d_out;                       // [N][256]
    float* out_p = out_q + (size_t)N * DD;              // [N][1024]

    unsigned short* cbA = (unsigned short*)d_ws;        // 576 KB fragment-major
    unsigned short* cbB = cbA + (size_t)64 * KC1 * 128; // 512 KB fragment-major
    vq_prep_kernel<<<VV, 256, 0, stream>>>(cb, cbA, cbB);
    vq_softmax_kernel<<<(N / BN) / TILES, 512, 0, stream>>>(x, gum, cbA, out_p);
    vq_gemm2_kernel<<<N / 64, 256, 0, stream>>>(out_p, cbB, out_q);
}